// Round 6
// baseline (198.428 us; speedup 1.0000x reference)
//
#include <hip/hip_runtime.h>

#define N_BINS 15
#define NSTATS (3 * N_BINS)   // counts[15], conf_sum[15], acc_sum[15]
#define NBLK   2048           // main grid = partials stride
#define ROWS   4              // rows per wave iteration

// ---- DPP cross-lane reduce (full-rate VALU) ----
// ctrl: quad_perm xor1 = 0xB1, quad_perm xor2 = 0x4E, row_ror:4 = 0x124, row_ror:8 = 0x128
template <int CTRL>
__device__ __forceinline__ float dpp_fmax(float x) {
    int xi = __float_as_int(x);
    int mv = __builtin_amdgcn_update_dpp(xi, xi, CTRL, 0xF, 0xF, true);
    return fmaxf(x, __int_as_float(mv));
}
template <int CTRL>
__device__ __forceinline__ float dpp_fadd(float x) {
    int xi = __float_as_int(x);
    int mv = __builtin_amdgcn_update_dpp(xi, xi, CTRL, 0xF, 0xF, true);
    return x + __int_as_float(mv);
}

// 64-lane reductions: validated 16-wide DPP chain, then xor16 (ds_swizzle), xor32 (shfl)
__device__ __forceinline__ float red64_fmax(float x) {
    x = dpp_fmax<0x128>(x);  // row_ror:8
    x = dpp_fmax<0x124>(x);  // row_ror:4
    x = dpp_fmax<0x4E>(x);   // quad_perm xor2
    x = dpp_fmax<0xB1>(x);   // quad_perm xor1
    x = fmaxf(x, __int_as_float(__builtin_amdgcn_ds_swizzle(__float_as_int(x), 0x401F))); // xor16
    x = fmaxf(x, __shfl_xor(x, 32));                                                      // xor32
    return x;
}
__device__ __forceinline__ float red64_fadd(float x) {
    x = dpp_fadd<0x128>(x);
    x = dpp_fadd<0x124>(x);
    x = dpp_fadd<0x4E>(x);
    x = dpp_fadd<0xB1>(x);
    x += __int_as_float(__builtin_amdgcn_ds_swizzle(__float_as_int(x), 0x401F));
    x += __shfl_xor(x, 32);
    return x;
}

__device__ __forceinline__ float local_max4(float4 v) {
    return fmaxf(fmaxf(v.x, v.y), fmaxf(v.z, v.w));
}
__device__ __forceinline__ float local_expsum4(float4 v) {
    return (__expf(v.x) + __expf(v.y)) + (__expf(v.z) + __expf(v.w));
}
__device__ __forceinline__ float sel4(float4 v, int c) {
    // element c (0..3) of this lane's float4
    return (c & 1) ? ((c & 2) ? v.w : v.y) : ((c & 2) ? v.z : v.x);
}

// ---------------- fast path: per-block partials, no global atomics ----------------

__global__ __launch_bounds__(256) void ece_main_p(const float* __restrict__ logits,
                                                  const int* __restrict__ labels,
                                                  float* __restrict__ partials, // [NSTATS][NBLK]
                                                  int n_rows) {
    __shared__ float sbins[NSTATS];
    for (int i = threadIdx.x; i < NSTATS; i += 256) sbins[i] = 0.0f;
    __syncthreads();

    const int lane  = threadIdx.x & 63;
    const int wv    = threadIdx.x >> 6;
    const int gwave = blockIdx.x * 4 + wv;
    const int step  = NBLK * 4 * ROWS;   // 32768 rows per grid round

    for (int base = gwave * ROWS; base < n_rows; base += step) {
        // One load instruction per ROW: 64 lanes x consecutive float4 = 1KB coalesced.
        const float4* p = reinterpret_cast<const float4*>(logits) + (unsigned)base * 64u + (unsigned)lane;
        float4 v0, v1, v2, v3;
        int lab0 = 0, lab1 = 0, lab2 = 0, lab3 = 0;
        const bool full = (base + ROWS <= n_rows);
        if (full) {
            v0 = p[0]; v1 = p[64]; v2 = p[128]; v3 = p[192];   // imm offsets 0/1024/2048/3072
            lab0 = labels[base]; lab1 = labels[base + 1];
            lab2 = labels[base + 2]; lab3 = labels[base + 3];
        } else {
            const float4 neg = make_float4(-1e30f, -1e30f, -1e30f, -1e30f);
            v0 = (base + 0 < n_rows) ? p[0]   : neg;
            v1 = (base + 1 < n_rows) ? p[64]  : neg;
            v2 = (base + 2 < n_rows) ? p[128] : neg;
            v3 = (base + 3 < n_rows) ? p[192] : neg;
            if (base + 0 < n_rows) lab0 = labels[base + 0];
            if (base + 1 < n_rows) lab1 = labels[base + 1];
            if (base + 2 < n_rows) lab2 = labels[base + 2];
            if (base + 3 < n_rows) lab3 = labels[base + 3];
        }

        // Local 4-element reductions per row (independent chains).
        float m0 = local_max4(v0), m1 = local_max4(v1), m2 = local_max4(v2), m3 = local_max4(v3);
        float s0 = local_expsum4(v0), s1 = local_expsum4(v1), s2 = local_expsum4(v2), s3 = local_expsum4(v3);

        // Owner-lane label-logit select: lane lab>>2 holds the label's element (lab&3).
        const float e0 = sel4(v0, lab0 & 3), e1 = sel4(v1, lab1 & 3);
        const float e2 = sel4(v2, lab2 & 3), e3 = sel4(v3, lab3 & 3);
        const bool o0 = ((lab0 >> 2) == lane), o1 = ((lab1 >> 2) == lane);
        const bool o2 = ((lab2 >> 2) == lane), o3 = ((lab3 >> 2) == lane);

        // 64-wide reductions (4 independent chains pipeline through VALU/LDS).
        m0 = red64_fmax(m0); m1 = red64_fmax(m1); m2 = red64_fmax(m2); m3 = red64_fmax(m3);
        s0 = red64_fadd(s0); s1 = red64_fadd(s1); s2 = red64_fadd(s2); s3 = red64_fadd(s3);

        // Owner lanes bin their rows directly (no cross-lane handoff needed).
        #define ECE_EMIT(J)                                                         \
        if (o##J && (base + J < n_rows)) {                                          \
            const float conf = __expf(m##J) / s##J;                                 \
            const float acc  = (e##J == m##J) ? 1.0f : 0.0f;                        \
            int bin = (int)ceilf(conf * 15.0f) - 1;                                 \
            bin = bin < 0 ? 0 : (bin > N_BINS - 1 ? N_BINS - 1 : bin);              \
            atomicAdd(&sbins[bin], 1.0f);                                           \
            atomicAdd(&sbins[N_BINS + bin], conf);                                  \
            atomicAdd(&sbins[2 * N_BINS + bin], acc);                               \
        }
        ECE_EMIT(0) ECE_EMIT(1) ECE_EMIT(2) ECE_EMIT(3)
        #undef ECE_EMIT
    }

    __syncthreads();
    // Unconditional write of all 45 slots -> no zeroing kernel needed.
    for (int i = threadIdx.x; i < NSTATS; i += 256)
        partials[i * NBLK + blockIdx.x] = sbins[i];
}

__global__ __launch_bounds__(1024) void ece_final_p(const float* __restrict__ partials,
                                                    float* __restrict__ out, float n) {
    __shared__ float stat[NSTATS];
    const int wv   = threadIdx.x >> 6;
    const int lane = threadIdx.x & 63;
    for (int s = wv; s < NSTATS; s += 16) {
        float acc = 0.0f;
        #pragma unroll 4
        for (int b = lane; b < NBLK; b += 64) acc += partials[s * NBLK + b];
        #pragma unroll
        for (int off = 32; off >= 1; off >>= 1) acc += __shfl_xor(acc, off);
        if (lane == 0) stat[s] = acc;
    }
    __syncthreads();
    if (threadIdx.x == 0) {
        float ece = 0.0f;
        for (int i = 0; i < N_BINS; ++i) {
            const float c = stat[i];
            if (c > 0.0f) {
                const float sc  = c < 1.0f ? 1.0f : c;
                const float gap = fabsf(stat[N_BINS + i] / sc - stat[2 * N_BINS + i] / sc);
                ece += gap * c / n;
            }
        }
        out[0] = ece;
    }
}

// ---------------- fallback path (ws too small): atomic version ----------------

__global__ void ece_zero_ws(float* __restrict__ ws) {
    int i = threadIdx.x;
    if (i < NSTATS) ws[i] = 0.0f;
}

__global__ __launch_bounds__(256) void ece_main_a(const float* __restrict__ logits,
                                                  const int* __restrict__ labels,
                                                  float* __restrict__ ws,
                                                  int n_rows) {
    __shared__ float sbins[NSTATS];
    for (int i = threadIdx.x; i < NSTATS; i += 256) sbins[i] = 0.0f;
    __syncthreads();

    const int lane  = threadIdx.x & 63;
    const int wv    = threadIdx.x >> 6;
    const int gwave = blockIdx.x * 4 + wv;
    const int step  = NBLK * 4 * ROWS;

    for (int base = gwave * ROWS; base < n_rows; base += step) {
        const float4* p = reinterpret_cast<const float4*>(logits) + (unsigned)base * 64u + (unsigned)lane;
        float4 v0, v1, v2, v3;
        int lab0 = 0, lab1 = 0, lab2 = 0, lab3 = 0;
        const bool full = (base + ROWS <= n_rows);
        if (full) {
            v0 = p[0]; v1 = p[64]; v2 = p[128]; v3 = p[192];
            lab0 = labels[base]; lab1 = labels[base + 1];
            lab2 = labels[base + 2]; lab3 = labels[base + 3];
        } else {
            const float4 neg = make_float4(-1e30f, -1e30f, -1e30f, -1e30f);
            v0 = (base + 0 < n_rows) ? p[0]   : neg;
            v1 = (base + 1 < n_rows) ? p[64]  : neg;
            v2 = (base + 2 < n_rows) ? p[128] : neg;
            v3 = (base + 3 < n_rows) ? p[192] : neg;
            if (base + 0 < n_rows) lab0 = labels[base + 0];
            if (base + 1 < n_rows) lab1 = labels[base + 1];
            if (base + 2 < n_rows) lab2 = labels[base + 2];
            if (base + 3 < n_rows) lab3 = labels[base + 3];
        }

        float m0 = local_max4(v0), m1 = local_max4(v1), m2 = local_max4(v2), m3 = local_max4(v3);
        float s0 = local_expsum4(v0), s1 = local_expsum4(v1), s2 = local_expsum4(v2), s3 = local_expsum4(v3);
        const float e0 = sel4(v0, lab0 & 3), e1 = sel4(v1, lab1 & 3);
        const float e2 = sel4(v2, lab2 & 3), e3 = sel4(v3, lab3 & 3);
        const bool o0 = ((lab0 >> 2) == lane), o1 = ((lab1 >> 2) == lane);
        const bool o2 = ((lab2 >> 2) == lane), o3 = ((lab3 >> 2) == lane);
        m0 = red64_fmax(m0); m1 = red64_fmax(m1); m2 = red64_fmax(m2); m3 = red64_fmax(m3);
        s0 = red64_fadd(s0); s1 = red64_fadd(s1); s2 = red64_fadd(s2); s3 = red64_fadd(s3);

        #define ECE_EMIT(J)                                                         \
        if (o##J && (base + J < n_rows)) {                                          \
            const float conf = __expf(m##J) / s##J;                                 \
            const float acc  = (e##J == m##J) ? 1.0f : 0.0f;                        \
            int bin = (int)ceilf(conf * 15.0f) - 1;                                 \
            bin = bin < 0 ? 0 : (bin > N_BINS - 1 ? N_BINS - 1 : bin);              \
            atomicAdd(&sbins[bin], 1.0f);                                           \
            atomicAdd(&sbins[N_BINS + bin], conf);                                  \
            atomicAdd(&sbins[2 * N_BINS + bin], acc);                               \
        }
        ECE_EMIT(0) ECE_EMIT(1) ECE_EMIT(2) ECE_EMIT(3)
        #undef ECE_EMIT
    }
    __syncthreads();
    for (int i = threadIdx.x; i < NSTATS; i += 256) {
        const float val = sbins[i];
        if (val != 0.0f) atomicAdd(&ws[i], val);
    }
}

__global__ void ece_final_a(const float* __restrict__ ws, float* __restrict__ out, float n) {
    float ece = 0.0f;
    for (int i = 0; i < N_BINS; ++i) {
        const float c = ws[i];
        if (c > 0.0f) {
            const float sc  = c < 1.0f ? 1.0f : c;
            const float gap = fabsf(ws[N_BINS + i] / sc - ws[2 * N_BINS + i] / sc);
            ece += gap * c / n;
        }
    }
    out[0] = ece;
}

// -----------------------------------------------------------------------------------

extern "C" void kernel_launch(void* const* d_in, const int* in_sizes, int n_in,
                              void* d_out, int out_size, void* d_ws, size_t ws_size,
                              hipStream_t stream) {
    const float* logits = (const float*)d_in[0];
    const int*   labels = (const int*)d_in[1];
    float* out = (float*)d_out;
    float* ws  = (float*)d_ws;
    const int n_rows = in_sizes[1];   // 1,000,000

    const size_t needed = (size_t)NSTATS * NBLK * sizeof(float);
    if (ws_size >= needed) {
        ece_main_p<<<NBLK, 256, 0, stream>>>(logits, labels, ws, n_rows);
        ece_final_p<<<1, 1024, 0, stream>>>(ws, out, (float)n_rows);
    } else {
        ece_zero_ws<<<1, 64, 0, stream>>>(ws);
        ece_main_a<<<NBLK, 256, 0, stream>>>(logits, labels, ws, n_rows);
        ece_final_a<<<1, 1, 0, stream>>>(ws, out, (float)n_rows);
    }
}

// Round 7
// 186.962 us; speedup vs baseline: 1.0613x; 1.0613x over previous
//
#include <hip/hip_runtime.h>

#define N_BINS 15
#define NSTATS (3 * N_BINS)   // counts[15], conf_sum[15], acc_sum[15]
#define NBLK   2048           // main grid = partials stride
#define ROWS   4              // one row per 16-lane group

// ---- DPP cross-lane reduce within 16-lane rows (full-rate VALU, no LDS) ----
// ctrl: quad_perm xor1 = 0xB1, quad_perm xor2 = 0x4E, row_ror:4 = 0x124, row_ror:8 = 0x128
template <int CTRL>
__device__ __forceinline__ float dpp_fmax(float x) {
    int xi = __float_as_int(x);
    int mv = __builtin_amdgcn_update_dpp(xi, xi, CTRL, 0xF, 0xF, true);
    return fmaxf(x, __int_as_float(mv));
}
template <int CTRL>
__device__ __forceinline__ float dpp_fadd(float x) {
    int xi = __float_as_int(x);
    int mv = __builtin_amdgcn_update_dpp(xi, xi, CTRL, 0xF, 0xF, true);
    return x + __int_as_float(mv);
}

// ---------------- fast path: per-block partials, no global atomics ----------------

__global__ __launch_bounds__(256) void ece_main_p(const float* __restrict__ logits,
                                                  const int* __restrict__ labels,
                                                  float* __restrict__ partials, // [NSTATS][NBLK]
                                                  int n_rows) {
    __shared__ float sbins[NSTATS];
    for (int i = threadIdx.x; i < NSTATS; i += 256) sbins[i] = 0.0f;
    __syncthreads();

    const int lane = threadIdx.x & 63;
    const int g    = lane >> 4;        // row within the wave's quad
    const int t    = lane & 15;        // position within the row (16 lanes/row)
    const int wv   = threadIdx.x >> 6;
    const int gwave = blockIdx.x * 4 + wv;
    const int step  = NBLK * 4 * ROWS; // 32768 rows per grid round

    for (int base = gwave * ROWS; base < n_rows; base += step) {
        const int  r     = base + g;
        const bool valid = (r < n_rows);

        // Lane owns 16 contiguous floats of its row (one 64B granule). 32-bit offsets.
        float4 v0, v1, v2, v3;
        float  lab_logit = 0.0f;
        if (valid) {
            const unsigned off4 = ((unsigned)r << 6) + ((unsigned)t << 2);
            const float4* p = reinterpret_cast<const float4*>(logits) + off4;
            v0 = p[0]; v1 = p[1]; v2 = p[2]; v3 = p[3];
            const int lab = labels[r];                      // broadcast within group
            lab_logit = logits[((unsigned)r << 8) + (unsigned)lab]; // L1/L2 hit; hidden under exps
        } else {
            v0 = v1 = v2 = v3 = make_float4(-1e30f, -1e30f, -1e30f, -1e30f);
        }

        // Local max over 16 + sum of exp over 16 (independent chains).
        float m = fmaxf(fmaxf(fmaxf(v0.x, v0.y), fmaxf(v0.z, v0.w)),
                        fmaxf(fmaxf(v1.x, v1.y), fmaxf(v1.z, v1.w)));
        m = fmaxf(m, fmaxf(fmaxf(fmaxf(v2.x, v2.y), fmaxf(v2.z, v2.w)),
                           fmaxf(fmaxf(v3.x, v3.y), fmaxf(v3.z, v3.w))));

        float s = ((__expf(v0.x) + __expf(v0.y)) + (__expf(v0.z) + __expf(v0.w)))
                + ((__expf(v1.x) + __expf(v1.y)) + (__expf(v1.z) + __expf(v1.w)))
                + ((__expf(v2.x) + __expf(v2.y)) + (__expf(v2.z) + __expf(v2.w)))
                + ((__expf(v3.x) + __expf(v3.y)) + (__expf(v3.z) + __expf(v3.w)));

        // Rotation/xor reduce within each 16-lane row: 8 full-rate DPP pairs.
        m = dpp_fmax<0x128>(m);  s = dpp_fadd<0x128>(s);   // row_ror:8
        m = dpp_fmax<0x124>(m);  s = dpp_fadd<0x124>(s);   // row_ror:4
        m = dpp_fmax<0x4E>(m);   s = dpp_fadd<0x4E>(s);    // quad_perm xor2
        m = dpp_fmax<0xB1>(m);   s = dpp_fadd<0xB1>(s);    // quad_perm xor1

        if (t == 0 && valid) {
            const float conf = __expf(m) / s;
            const float acc  = (lab_logit == m) ? 1.0f : 0.0f;

            // searchsorted(linspace(0,1,16), conf, 'left')-1  ==  ceil(conf*15)-1 (clipped)
            int bin = (int)ceilf(conf * 15.0f) - 1;
            bin = bin < 0 ? 0 : (bin > N_BINS - 1 ? N_BINS - 1 : bin);

            atomicAdd(&sbins[bin], 1.0f);
            atomicAdd(&sbins[N_BINS + bin], conf);
            atomicAdd(&sbins[2 * N_BINS + bin], acc);
        }
    }

    __syncthreads();
    // Unconditional write of all 45 slots -> no zeroing kernel needed.
    for (int i = threadIdx.x; i < NSTATS; i += 256)
        partials[i * NBLK + blockIdx.x] = sbins[i];
}

__global__ __launch_bounds__(1024) void ece_final_p(const float* __restrict__ partials,
                                                    float* __restrict__ out, float n) {
    __shared__ float stat[NSTATS];
    const int wv   = threadIdx.x >> 6;
    const int lane = threadIdx.x & 63;
    for (int s = wv; s < NSTATS; s += 16) {
        float acc = 0.0f;
        #pragma unroll 4
        for (int b = lane; b < NBLK; b += 64) acc += partials[s * NBLK + b];
        #pragma unroll
        for (int off = 32; off >= 1; off >>= 1) acc += __shfl_xor(acc, off);
        if (lane == 0) stat[s] = acc;
    }
    __syncthreads();
    if (threadIdx.x == 0) {
        float ece = 0.0f;
        for (int i = 0; i < N_BINS; ++i) {
            const float c = stat[i];
            if (c > 0.0f) {
                const float sc  = c < 1.0f ? 1.0f : c;
                const float gap = fabsf(stat[N_BINS + i] / sc - stat[2 * N_BINS + i] / sc);
                ece += gap * c / n;
            }
        }
        out[0] = ece;
    }
}

// ---------------- fallback path (ws too small): atomic version ----------------

__global__ void ece_zero_ws(float* __restrict__ ws) {
    int i = threadIdx.x;
    if (i < NSTATS) ws[i] = 0.0f;
}

__global__ __launch_bounds__(256) void ece_main_a(const float* __restrict__ logits,
                                                  const int* __restrict__ labels,
                                                  float* __restrict__ ws,
                                                  int n_rows) {
    __shared__ float sbins[NSTATS];
    for (int i = threadIdx.x; i < NSTATS; i += 256) sbins[i] = 0.0f;
    __syncthreads();

    const int lane = threadIdx.x & 63;
    const int g = lane >> 4, t = lane & 15;
    const int wv = threadIdx.x >> 6;
    const int gwave = blockIdx.x * 4 + wv;
    const int step  = NBLK * 4 * ROWS;

    for (int base = gwave * ROWS; base < n_rows; base += step) {
        const int  r     = base + g;
        const bool valid = (r < n_rows);
        float4 v0, v1, v2, v3;
        float lab_logit = 0.0f;
        if (valid) {
            const unsigned off4 = ((unsigned)r << 6) + ((unsigned)t << 2);
            const float4* p = reinterpret_cast<const float4*>(logits) + off4;
            v0 = p[0]; v1 = p[1]; v2 = p[2]; v3 = p[3];
            const int lab = labels[r];
            lab_logit = logits[((unsigned)r << 8) + (unsigned)lab];
        } else {
            v0 = v1 = v2 = v3 = make_float4(-1e30f, -1e30f, -1e30f, -1e30f);
        }
        float m = fmaxf(fmaxf(fmaxf(v0.x, v0.y), fmaxf(v0.z, v0.w)),
                        fmaxf(fmaxf(v1.x, v1.y), fmaxf(v1.z, v1.w)));
        m = fmaxf(m, fmaxf(fmaxf(fmaxf(v2.x, v2.y), fmaxf(v2.z, v2.w)),
                           fmaxf(fmaxf(v3.x, v3.y), fmaxf(v3.z, v3.w))));
        float s = ((__expf(v0.x) + __expf(v0.y)) + (__expf(v0.z) + __expf(v0.w)))
                + ((__expf(v1.x) + __expf(v1.y)) + (__expf(v1.z) + __expf(v1.w)))
                + ((__expf(v2.x) + __expf(v2.y)) + (__expf(v2.z) + __expf(v2.w)))
                + ((__expf(v3.x) + __expf(v3.y)) + (__expf(v3.z) + __expf(v3.w)));
        m = dpp_fmax<0x128>(m);  s = dpp_fadd<0x128>(s);
        m = dpp_fmax<0x124>(m);  s = dpp_fadd<0x124>(s);
        m = dpp_fmax<0x4E>(m);   s = dpp_fadd<0x4E>(s);
        m = dpp_fmax<0xB1>(m);   s = dpp_fadd<0xB1>(s);
        if (t == 0 && valid) {
            const float conf = __expf(m) / s;
            const float acc  = (lab_logit == m) ? 1.0f : 0.0f;
            int bin = (int)ceilf(conf * 15.0f) - 1;
            bin = bin < 0 ? 0 : (bin > N_BINS - 1 ? N_BINS - 1 : bin);
            atomicAdd(&sbins[bin], 1.0f);
            atomicAdd(&sbins[N_BINS + bin], conf);
            atomicAdd(&sbins[2 * N_BINS + bin], acc);
        }
    }
    __syncthreads();
    for (int i = threadIdx.x; i < NSTATS; i += 256) {
        const float val = sbins[i];
        if (val != 0.0f) atomicAdd(&ws[i], val);
    }
}

__global__ void ece_final_a(const float* __restrict__ ws, float* __restrict__ out, float n) {
    float ece = 0.0f;
    for (int i = 0; i < N_BINS; ++i) {
        const float c = ws[i];
        if (c > 0.0f) {
            const float sc  = c < 1.0f ? 1.0f : c;
            const float gap = fabsf(ws[N_BINS + i] / sc - ws[2 * N_BINS + i] / sc);
            ece += gap * c / n;
        }
    }
    out[0] = ece;
}

// -----------------------------------------------------------------------------------

extern "C" void kernel_launch(void* const* d_in, const int* in_sizes, int n_in,
                              void* d_out, int out_size, void* d_ws, size_t ws_size,
                              hipStream_t stream) {
    const float* logits = (const float*)d_in[0];
    const int*   labels = (const int*)d_in[1];
    float* out = (float*)d_out;
    float* ws  = (float*)d_ws;
    const int n_rows = in_sizes[1];   // 1,000,000

    const size_t needed = (size_t)NSTATS * NBLK * sizeof(float);
    if (ws_size >= needed) {
        ece_main_p<<<NBLK, 256, 0, stream>>>(logits, labels, ws, n_rows);
        ece_final_p<<<1, 1024, 0, stream>>>(ws, out, (float)n_rows);
    } else {
        ece_zero_ws<<<1, 64, 0, stream>>>(ws);
        ece_main_a<<<NBLK, 256, 0, stream>>>(logits, labels, ws, n_rows);
        ece_final_a<<<1, 1, 0, stream>>>(ws, out, (float)n_rows);
    }
}